// Round 2
// baseline (2013.832 us; speedup 1.0000x reference)
//
#include <hip/hip_runtime.h>

typedef __attribute__((ext_vector_type(8))) short bf16x8;
typedef __attribute__((ext_vector_type(4))) float f32x4;

#define DI __device__ __forceinline__

// Problem constants (B,S,D)=(2,2048,2048), H=16, KV=4, HD=128
constexpr int CB = 2, CS = 2048, CD = 2048, CH = 16, CKV = 4, CHD = 128, CNREP = 4;

DI unsigned short f2bf(float f) {
  unsigned u = __builtin_bit_cast(unsigned, f);
  u += 0x7fffu + ((u >> 16) & 1u);   // RNE
  return (unsigned short)(u >> 16);
}

// ---------------------------------------------------------------------------
// Generic GEMM: C(M,N) = A(M,K) @ B(K,N); A,B,C f32 row-major; bf16 MFMA inner.
// 64x64 tile, BK=32, 256 threads = 4 waves; wave w owns rows [w*16, w*16+16).
// mfma_f32_16x16x32_bf16 layouts:
//   A frag: row = lane&15, k = (lane>>4)*8 + j
//   B frag: col = lane&15, k = (lane>>4)*8 + j
//   C/D   : col = lane&15, row = (lane>>4)*4 + reg   [verified, learn_hip m89]
// LDS row stride = 40 shorts (80B): 16B-aligned b128 frag reads, 2-way banks.
// ---------------------------------------------------------------------------
__global__ __launch_bounds__(256) void gemm_rr_bf16(
    const float* __restrict__ A, const float* __restrict__ Bm,
    float* __restrict__ C, int M, int N, int Kd)
{
  __shared__ __align__(16) unsigned short As[64][40];
  __shared__ __align__(16) unsigned short Bs[64][40];

  const int t  = threadIdx.x;
  const int m0 = blockIdx.y * 64;
  const int n0 = blockIdx.x * 64;
  const int w  = t >> 6;
  const int l  = t & 63;
  const int lr = l & 15;
  const int k0 = (l >> 4) << 3;

  // staging assignment
  const int arow = t >> 2;          // 0..63
  const int ak   = (t & 3) << 3;    // 0,8,16,24
  const int bcol = t & 63;          // 0..63
  const int bk   = (t >> 6) << 3;   // 0,8,16,24

  const float* ap = A  + (size_t)(m0 + arow) * Kd + ak;
  const float* bp = Bm + (size_t)bk * N + n0 + bcol;

  f32x4 acc[4];
#pragma unroll
  for (int i = 0; i < 4; ++i) acc[i] = (f32x4){0.f, 0.f, 0.f, 0.f};

  for (int kt = 0; kt < Kd; kt += 32) {
    // global -> regs (f32)
    float4 a0 = *(const float4*)(ap);
    float4 a1 = *(const float4*)(ap + 4);
    float bv[8];
#pragma unroll
    for (int i = 0; i < 8; ++i) bv[i] = bp[(size_t)i * N];
    ap += 32;
    bp += (size_t)32 * N;

    __syncthreads();   // previous iteration's frag reads done

    bf16x8 av;
    av[0] = f2bf(a0.x); av[1] = f2bf(a0.y); av[2] = f2bf(a0.z); av[3] = f2bf(a0.w);
    av[4] = f2bf(a1.x); av[5] = f2bf(a1.y); av[6] = f2bf(a1.z); av[7] = f2bf(a1.w);
    *(bf16x8*)&As[arow][ak] = av;

    bf16x8 bvv;
#pragma unroll
    for (int i = 0; i < 8; ++i) bvv[i] = f2bf(bv[i]);
    *(bf16x8*)&Bs[bcol][bk] = bvv;   // stored transposed: [col][k]

    __syncthreads();   // tiles visible

    bf16x8 aF = *(const bf16x8*)&As[w * 16 + lr][k0];
    bf16x8 b0 = *(const bf16x8*)&Bs[ 0 + lr][k0];
    bf16x8 b1 = *(const bf16x8*)&Bs[16 + lr][k0];
    bf16x8 b2 = *(const bf16x8*)&Bs[32 + lr][k0];
    bf16x8 b3 = *(const bf16x8*)&Bs[48 + lr][k0];

    acc[0] = __builtin_amdgcn_mfma_f32_16x16x32_bf16(aF, b0, acc[0], 0, 0, 0);
    acc[1] = __builtin_amdgcn_mfma_f32_16x16x32_bf16(aF, b1, acc[1], 0, 0, 0);
    acc[2] = __builtin_amdgcn_mfma_f32_16x16x32_bf16(aF, b2, acc[2], 0, 0, 0);
    acc[3] = __builtin_amdgcn_mfma_f32_16x16x32_bf16(aF, b3, acc[3], 0, 0, 0);
  }

  const int row0 = m0 + w * 16 + ((l >> 4) << 2);
#pragma unroll
  for (int j = 0; j < 4; ++j) {
    float* cp = C + (size_t)(row0 + j) * N + n0 + lr;
    cp[0]  = acc[0][j];
    cp[16] = acc[1][j];
    cp[32] = acc[2][j];
    cp[48] = acc[3][j];
  }
}

// ---------------------------------------------------------------------------
// RoPE in-place on [B][S][nH][128]; pair p uses cos/sin[s][p]. scale folds
// the 1/sqrt(HD) attention scaling into Q (scale=1 for K).
// ---------------------------------------------------------------------------
__global__ void rope_kernel(float* __restrict__ tq, const float* __restrict__ cosT,
                            const float* __restrict__ sinT, int nH, float scale,
                            int total)
{
  int idx = blockIdx.x * blockDim.x + threadIdx.x;
  if (idx >= total) return;
  const int p    = idx & 63;
  const int rest = idx >> 6;                 // = (b*S + s)*nH + h
  const int s    = (rest / nH) & (CS - 1);
  const float c  = cosT[s * 64 + p];
  const float sn = sinT[s * 64 + p];
  float* ptr = tq + (size_t)rest * CHD;
  const float re = ptr[2 * p], im = ptr[2 * p + 1];
  ptr[2 * p]     = (re * c - im * sn) * scale;
  ptr[2 * p + 1] = (re * sn + im * c) * scale;
}

// ---------------------------------------------------------------------------
// Causal GQA flash attention, f32 vector compute (round-0 baseline).
// Block = 256 threads, one (b, h, 32-row q-tile). K/V tiles of 32 staged in
// LDS; online softmax (running m,l per row). Writes output IN-PLACE over Q.
//   Q: [B][S][H][HD] (roped, pre-scaled)   K,V: [B][S][KV][HD] (K roped)
// ---------------------------------------------------------------------------
__global__ __launch_bounds__(256) void attn_kernel(
    const float* __restrict__ Q, const float* __restrict__ K,
    const float* __restrict__ V, float* __restrict__ O)
{
  constexpr int QT = 32, KT = 32, PAD = 132, SP = 33;
  __shared__ float Qs[QT][PAD];
  __shared__ float Ks[KT][PAD];
  __shared__ float Vs[KT][PAD];
  __shared__ float Ss[QT][SP];
  __shared__ float rowM[QT], rowL[QT], rowScale[QT];

  const int t  = threadIdx.x;
  const int qt = blockIdx.x, h = blockIdx.y, b = blockIdx.z;
  const int kvh = h / CNREP;
  const int q0  = qt * QT;

  // load Q tile (float4-coalesced)
  for (int i = t; i < QT * 32; i += 256) {
    const int r = i >> 5, dd = (i & 31) << 2;
    *(float4*)&Qs[r][dd] =
        *(const float4*)&Q[(((size_t)(b * CS + q0 + r) * CH) + h) * CHD + dd];
  }
  if (t < QT) { rowM[t] = -1e30f; rowL[t] = 0.f; }

  float acc[4][4] = {};
  const int dgrp = t & 31, rgrp = t >> 5;
  const int d0 = dgrp << 2, r0 = rgrp << 2;
  __syncthreads();

  for (int kt = 0; kt < q0 + QT; kt += KT) {
    // stage K,V tiles
    for (int i = t; i < KT * 32; i += 256) {
      const int r = i >> 5, dd = (i & 31) << 2;
      const size_t g = (((size_t)(b * CS + kt + r) * CKV) + kvh) * CHD + dd;
      *(float4*)&Ks[r][dd] = *(const float4*)&K[g];
      *(float4*)&Vs[r][dd] = *(const float4*)&V[g];
    }
    __syncthreads();

    // scores: thread -> row sr, 4 cols sc..sc+3
    {
      const int sr = t >> 3, sc = (t & 7) << 2;
      float s0 = 0.f, s1 = 0.f, s2 = 0.f, s3 = 0.f;
      for (int dd = 0; dd < CHD; dd += 4) {
        const float4 qv  = *(const float4*)&Qs[sr][dd];
        const float4 kv0 = *(const float4*)&Ks[sc + 0][dd];
        const float4 kv1 = *(const float4*)&Ks[sc + 1][dd];
        const float4 kv2 = *(const float4*)&Ks[sc + 2][dd];
        const float4 kv3 = *(const float4*)&Ks[sc + 3][dd];
        s0 += qv.x * kv0.x + qv.y * kv0.y + qv.z * kv0.z + qv.w * kv0.w;
        s1 += qv.x * kv1.x + qv.y * kv1.y + qv.z * kv1.z + qv.w * kv1.w;
        s2 += qv.x * kv2.x + qv.y * kv2.y + qv.z * kv2.z + qv.w * kv2.w;
        s3 += qv.x * kv3.x + qv.y * kv3.y + qv.z * kv3.z + qv.w * kv3.w;
      }
      const int qg = q0 + sr;
      Ss[sr][sc + 0] = (kt + sc + 0 <= qg) ? s0 : -1e30f;
      Ss[sr][sc + 1] = (kt + sc + 1 <= qg) ? s1 : -1e30f;
      Ss[sr][sc + 2] = (kt + sc + 2 <= qg) ? s2 : -1e30f;
      Ss[sr][sc + 3] = (kt + sc + 3 <= qg) ? s3 : -1e30f;
    }
    __syncthreads();

    // per-row online-softmax stats (one lane per row)
    if (t < QT) {
      const float mo = rowM[t];
      float mx = mo;
#pragma unroll
      for (int k2 = 0; k2 < KT; ++k2) mx = fmaxf(mx, Ss[t][k2]);
      float sum = 0.f;
#pragma unroll
      for (int k2 = 0; k2 < KT; ++k2) {
        const float p = __expf(Ss[t][k2] - mx);
        Ss[t][k2] = p;
        sum += p;
      }
      const float scl = __expf(mo - mx);
      rowScale[t] = scl;
      rowL[t] = rowL[t] * scl + sum;
      rowM[t] = mx;
    }
    __syncthreads();

    // PV accumulate: thread owns rows r0..r0+3 x dims d0..d0+3
#pragma unroll
    for (int rr = 0; rr < 4; ++rr) {
      const float scl = rowScale[r0 + rr];
      float a0 = acc[rr][0] * scl, a1 = acc[rr][1] * scl;
      float a2 = acc[rr][2] * scl, a3 = acc[rr][3] * scl;
      for (int k2 = 0; k2 < KT; ++k2) {
        const float p = Ss[r0 + rr][k2];
        const float4 vv = *(const float4*)&Vs[k2][d0];
        a0 += p * vv.x; a1 += p * vv.y; a2 += p * vv.z; a3 += p * vv.w;
      }
      acc[rr][0] = a0; acc[rr][1] = a1; acc[rr][2] = a2; acc[rr][3] = a3;
    }
    __syncthreads();
  }

  // epilogue: normalize and store (in-place over Q is safe: this block's Q
  // slice already lives in LDS and no other block reads it)
#pragma unroll
  for (int rr = 0; rr < 4; ++rr) {
    const float inv = 1.f / rowL[r0 + rr];
    float4 o;
    o.x = acc[rr][0] * inv; o.y = acc[rr][1] * inv;
    o.z = acc[rr][2] * inv; o.w = acc[rr][3] * inv;
    *(float4*)&O[(((size_t)(b * CS + q0 + r0 + rr) * CH) + h) * CHD + d0] = o;
  }
}

// ---------------------------------------------------------------------------
extern "C" void kernel_launch(void* const* d_in, const int* in_sizes, int n_in,
                              void* d_out, int out_size, void* d_ws, size_t ws_size,
                              hipStream_t stream)
{
  const float* x  = (const float*)d_in[0];
  const float* wq = (const float*)d_in[1];
  const float* wk = (const float*)d_in[2];
  const float* wv = (const float*)d_in[3];
  const float* wo = (const float*)d_in[4];
  const float* fc = (const float*)d_in[5];
  const float* fs = (const float*)d_in[6];
  float* out = (float*)d_out;

  // workspace: q [B,S,H,HD] | k [B,S,KV,HD] | v [B,S,KV,HD]  (50.3 MB f32)
  float* q = (float*)d_ws;
  float* k = q + (size_t)CB * CS * CH * CHD;    // + 8388608
  float* v = k + (size_t)CB * CS * CKV * CHD;   // + 2097152

  const int M = CB * CS;  // 4096
  dim3 blk(256);

  gemm_rr_bf16<<<dim3(CH * CHD / 64, M / 64), blk, 0, stream>>>(x, wq, q, M, CH * CHD, CD);
  gemm_rr_bf16<<<dim3(CKV * CHD / 64, M / 64), blk, 0, stream>>>(x, wk, k, M, CKV * CHD, CD);
  gemm_rr_bf16<<<dim3(CKV * CHD / 64, M / 64), blk, 0, stream>>>(x, wv, v, M, CKV * CHD, CD);

  const int qpairs = CB * CS * CH * (CHD / 2);   // 4,194,304
  const int kpairs = CB * CS * CKV * (CHD / 2);  // 1,048,576
  rope_kernel<<<(qpairs + 255) / 256, 256, 0, stream>>>(q, fc, fs, CH, 0.08838834764831845f, qpairs);
  rope_kernel<<<(kpairs + 255) / 256, 256, 0, stream>>>(k, fc, fs, CKV, 1.0f, kpairs);

  attn_kernel<<<dim3(CS / 32, CH, CB), blk, 0, stream>>>(q, k, v, q);

  gemm_rr_bf16<<<dim3(CD / 64, M / 64), blk, 0, stream>>>(q, wo, out, M, CD, CD);
}

// Round 3
// 829.026 us; speedup vs baseline: 2.4292x; 2.4292x over previous
//
#include <hip/hip_runtime.h>

typedef __attribute__((ext_vector_type(8))) short bf16x8;
typedef __attribute__((ext_vector_type(4))) float f32x4;

#define DI __device__ __forceinline__

// Problem constants (B,S,D)=(2,2048,2048), H=16, KV=4, HD=128
constexpr int CB = 2, CS = 2048, CD = 2048, CH = 16, CKV = 4, CHD = 128, CNREP = 4;

DI unsigned short f2bf(float f) {
  unsigned u = __builtin_bit_cast(unsigned, f);
  u += 0x7fffu + ((u >> 16) & 1u);   // RNE
  return (unsigned short)(u >> 16);
}

// ---------------------------------------------------------------------------
// Generic GEMM: C(M,N) = A(M,K) @ B(K,N); A,B,C f32 row-major; bf16 MFMA inner.
// (unchanged from round 0 — passed; upgrade planned next round)
// ---------------------------------------------------------------------------
__global__ __launch_bounds__(256) void gemm_rr_bf16(
    const float* __restrict__ A, const float* __restrict__ Bm,
    float* __restrict__ C, int M, int N, int Kd)
{
  __shared__ __align__(16) unsigned short As[64][40];
  __shared__ __align__(16) unsigned short Bs[64][40];

  const int t  = threadIdx.x;
  const int m0 = blockIdx.y * 64;
  const int n0 = blockIdx.x * 64;
  const int w  = t >> 6;
  const int l  = t & 63;
  const int lr = l & 15;
  const int k0 = (l >> 4) << 3;

  const int arow = t >> 2;          // 0..63
  const int ak   = (t & 3) << 3;    // 0,8,16,24
  const int bcol = t & 63;          // 0..63
  const int bk   = (t >> 6) << 3;   // 0,8,16,24

  const float* ap = A  + (size_t)(m0 + arow) * Kd + ak;
  const float* bp = Bm + (size_t)bk * N + n0 + bcol;

  f32x4 acc[4];
#pragma unroll
  for (int i = 0; i < 4; ++i) acc[i] = (f32x4){0.f, 0.f, 0.f, 0.f};

  for (int kt = 0; kt < Kd; kt += 32) {
    float4 a0 = *(const float4*)(ap);
    float4 a1 = *(const float4*)(ap + 4);
    float bv[8];
#pragma unroll
    for (int i = 0; i < 8; ++i) bv[i] = bp[(size_t)i * N];
    ap += 32;
    bp += (size_t)32 * N;

    __syncthreads();

    bf16x8 av;
    av[0] = f2bf(a0.x); av[1] = f2bf(a0.y); av[2] = f2bf(a0.z); av[3] = f2bf(a0.w);
    av[4] = f2bf(a1.x); av[5] = f2bf(a1.y); av[6] = f2bf(a1.z); av[7] = f2bf(a1.w);
    *(bf16x8*)&As[arow][ak] = av;

    bf16x8 bvv;
#pragma unroll
    for (int i = 0; i < 8; ++i) bvv[i] = f2bf(bv[i]);
    *(bf16x8*)&Bs[bcol][bk] = bvv;

    __syncthreads();

    bf16x8 aF = *(const bf16x8*)&As[w * 16 + lr][k0];
    bf16x8 b0 = *(const bf16x8*)&Bs[ 0 + lr][k0];
    bf16x8 b1 = *(const bf16x8*)&Bs[16 + lr][k0];
    bf16x8 b2 = *(const bf16x8*)&Bs[32 + lr][k0];
    bf16x8 b3 = *(const bf16x8*)&Bs[48 + lr][k0];

    acc[0] = __builtin_amdgcn_mfma_f32_16x16x32_bf16(aF, b0, acc[0], 0, 0, 0);
    acc[1] = __builtin_amdgcn_mfma_f32_16x16x32_bf16(aF, b1, acc[1], 0, 0, 0);
    acc[2] = __builtin_amdgcn_mfma_f32_16x16x32_bf16(aF, b2, acc[2], 0, 0, 0);
    acc[3] = __builtin_amdgcn_mfma_f32_16x16x32_bf16(aF, b3, acc[3], 0, 0, 0);
  }

  const int row0 = m0 + w * 16 + ((l >> 4) << 2);
#pragma unroll
  for (int j = 0; j < 4; ++j) {
    float* cp = C + (size_t)(row0 + j) * N + n0 + lr;
    cp[0]  = acc[0][j];
    cp[16] = acc[1][j];
    cp[32] = acc[2][j];
    cp[48] = acc[3][j];
  }
}

// ---------------------------------------------------------------------------
// RoPE in-place on [B][S][nH][128]; scale folds 1/sqrt(HD) into Q.
// ---------------------------------------------------------------------------
__global__ void rope_kernel(float* __restrict__ tq, const float* __restrict__ cosT,
                            const float* __restrict__ sinT, int nH, float scale,
                            int total)
{
  int idx = blockIdx.x * blockDim.x + threadIdx.x;
  if (idx >= total) return;
  const int p    = idx & 63;
  const int rest = idx >> 6;                 // = (b*S + s)*nH + h
  const int s    = (rest / nH) & (CS - 1);
  const float c  = cosT[s * 64 + p];
  const float sn = sinT[s * 64 + p];
  float* ptr = tq + (size_t)rest * CHD;
  const float re = ptr[2 * p], im = ptr[2 * p + 1];
  ptr[2 * p]     = (re * c - im * sn) * scale;
  ptr[2 * p + 1] = (re * sn + im * c) * scale;
}

// ---------------------------------------------------------------------------
// MFMA causal GQA flash attention (bf16 compute, f32 accum).
// Block = 256 thr = 4 waves, owns 64 q-rows of one (b,h). Wave w: rows w*16..+16.
// Per 64-key tile: K bf16 LDS [64][136] (row=key -> B-frag b128 reads),
// V bf16 LDS transposed [128][72] (row=d -> PV B-frag b128 reads),
// P per-wave LDS [16][72] (C-layout scalar writes -> A-frag b128 reads).
// Verified mfma_f32_16x16x32_bf16 layouts (same as passing GEMM):
//   A: row=lane&15, k=(lane>>4)*8+j | B: col=lane&15, k=(lane>>4)*8+j
//   C/D: col=lane&15, row=(lane>>4)*4+reg
// ---------------------------------------------------------------------------
__global__ __launch_bounds__(256) void attn_mfma(
    const float* __restrict__ Q, const float* __restrict__ K,
    const float* __restrict__ V, float* __restrict__ O)
{
  constexpr int KSTR = 136;   // shorts; 272B row = 16B-aligned, bank-spread
  constexpr int VSTR = 72;    // shorts; 144B row
  constexpr int PSTR = 72;
  __shared__ __align__(16) unsigned short lds[64 * KSTR + 128 * VSTR + 4 * 16 * PSTR];
  unsigned short* KsB = lds;                          // [64][KSTR]
  unsigned short* VtB = lds + 64 * KSTR;              // [128][VSTR]  (Vt[d][key])
  unsigned short* PsB = lds + 64 * KSTR + 128 * VSTR; // [4][16][PSTR]

  const int t   = threadIdx.x;
  const int w   = t >> 6, l = t & 63;
  const int l15 = l & 15, lg = l >> 4;
  const int qt = blockIdx.x, h = blockIdx.y, b = blockIdx.z;
  const int kvh = h >> 2;           // h / CNREP
  const int q0  = qt * 64;

  // ---- stage Q tile (f32 -> bf16) into lds (reused region), coalesced
  {
    unsigned short* Qs = lds;
    for (int i = t; i < 64 * 32; i += 256) {
      const int r = i >> 5, d4 = (i & 31) << 2;
      const float4 f = *(const float4*)&Q[(((size_t)(b * CS + q0 + r)) * CH + h) * CHD + d4];
      unsigned short v4[4] = {f2bf(f.x), f2bf(f.y), f2bf(f.z), f2bf(f.w)};
      *(unsigned long long*)&Qs[r * KSTR + d4] = *(unsigned long long*)v4;
    }
  }
  __syncthreads();

  // ---- Q frags to registers: row = w*16 + l15, 4 k-slices
  bf16x8 qf[4];
  {
    unsigned short* Qs = lds;
#pragma unroll
    for (int kk = 0; kk < 4; ++kk)
      qf[kk] = *(const bf16x8*)&Qs[(w * 16 + l15) * KSTR + kk * 32 + lg * 8];
  }
  __syncthreads();   // Q consumed; LDS handed over to K/Vt/P

  f32x4 accO[8];
#pragma unroll
  for (int i = 0; i < 8; ++i) accO[i] = (f32x4){0.f, 0.f, 0.f, 0.f};
  float m_j[4] = {-1e30f, -1e30f, -1e30f, -1e30f};
  float l_j[4] = {0.f, 0.f, 0.f, 0.f};

  for (int kt = 0; kt <= q0; kt += 64) {
    const bool maskedTile = (kt == q0);

    // ---- stage K rows (coalesced float4 -> bf16x4)
    for (int i = t; i < 64 * 32; i += 256) {
      const int r = i >> 5, d4 = (i & 31) << 2;
      const float4 f = *(const float4*)&K[(((size_t)(b * CS + kt + r)) * CKV + kvh) * CHD + d4];
      unsigned short v4[4] = {f2bf(f.x), f2bf(f.y), f2bf(f.z), f2bf(f.w)};
      *(unsigned long long*)&KsB[r * KSTR + d4] = *(unsigned long long*)v4;
    }
    // ---- stage V transposed: key-pairs packed as u32 into Vt[d][key]
    for (int i = t; i < 32 * 32; i += 256) {
      const int kp = i & 31, dg = i >> 5;        // key-pair, d-group(4)
      const int r  = kp * 2;
      const size_t g0 = (((size_t)(b * CS + kt + r)) * CKV + kvh) * CHD + dg * 4;
      const float4 v0 = *(const float4*)&V[g0];
      const float4 v1 = *(const float4*)&V[g0 + (size_t)CKV * CHD];
      *(unsigned*)&VtB[(dg * 4 + 0) * VSTR + r] = (unsigned)f2bf(v0.x) | ((unsigned)f2bf(v1.x) << 16);
      *(unsigned*)&VtB[(dg * 4 + 1) * VSTR + r] = (unsigned)f2bf(v0.y) | ((unsigned)f2bf(v1.y) << 16);
      *(unsigned*)&VtB[(dg * 4 + 2) * VSTR + r] = (unsigned)f2bf(v0.z) | ((unsigned)f2bf(v1.z) << 16);
      *(unsigned*)&VtB[(dg * 4 + 3) * VSTR + r] = (unsigned)f2bf(v0.w) | ((unsigned)f2bf(v1.w) << 16);
    }
    __syncthreads();

    // ---- QK^T: S(16 x 64) per wave, 4 key-subtiles x 4 k-slices
    f32x4 s[4];
#pragma unroll
    for (int ks = 0; ks < 4; ++ks) s[ks] = (f32x4){0.f, 0.f, 0.f, 0.f};
#pragma unroll
    for (int kk = 0; kk < 4; ++kk) {
#pragma unroll
      for (int ks = 0; ks < 4; ++ks) {
        const bf16x8 bf = *(const bf16x8*)&KsB[(ks * 16 + l15) * KSTR + kk * 32 + lg * 8];
        s[ks] = __builtin_amdgcn_mfma_f32_16x16x32_bf16(qf[kk], bf, s[ks], 0, 0, 0);
      }
    }

    // ---- causal mask on the diagonal tile
    if (maskedTile) {
      const int qr = q0 + w * 16 + lg * 4;
#pragma unroll
      for (int ks = 0; ks < 4; ++ks) {
        const int kg = kt + ks * 16 + l15;
#pragma unroll
        for (int j = 0; j < 4; ++j)
          if (kg > qr + j) s[ks][j] = -1e30f;
      }
    }

    // ---- online softmax (rows spread over 16-lane groups; 4 rows/lane)
    float rs[4];
#pragma unroll
    for (int j = 0; j < 4; ++j) {
      float mx = fmaxf(fmaxf(s[0][j], s[1][j]), fmaxf(s[2][j], s[3][j]));
      mx = fmaxf(mx, __shfl_xor(mx, 1));
      mx = fmaxf(mx, __shfl_xor(mx, 2));
      mx = fmaxf(mx, __shfl_xor(mx, 4));
      mx = fmaxf(mx, __shfl_xor(mx, 8));
      const float mnew = fmaxf(m_j[j], mx);
      float sum = 0.f;
#pragma unroll
      for (int ks = 0; ks < 4; ++ks) {
        const float p = __expf(s[ks][j] - mnew);
        s[ks][j] = p;
        sum += p;
      }
      sum += __shfl_xor(sum, 1);
      sum += __shfl_xor(sum, 2);
      sum += __shfl_xor(sum, 4);
      sum += __shfl_xor(sum, 8);
      rs[j]  = __expf(m_j[j] - mnew);
      l_j[j] = l_j[j] * rs[j] + sum;
      m_j[j] = mnew;
    }
#pragma unroll
    for (int d8 = 0; d8 < 8; ++d8)
#pragma unroll
      for (int j = 0; j < 4; ++j) accO[d8][j] *= rs[j];

    // ---- P (C-layout) -> per-wave LDS as bf16
    unsigned short* Pw = PsB + w * 16 * PSTR;
#pragma unroll
    for (int ks = 0; ks < 4; ++ks)
#pragma unroll
      for (int j = 0; j < 4; ++j)
        Pw[(lg * 4 + j) * PSTR + ks * 16 + l15] = f2bf(s[ks][j]);

    // ---- PV: O(16 x 128) += P(16 x 64) @ V(64 x 128)
#pragma unroll
    for (int k2 = 0; k2 < 2; ++k2) {
      const bf16x8 pa = *(const bf16x8*)&Pw[l15 * PSTR + k2 * 32 + lg * 8];
#pragma unroll
      for (int d8 = 0; d8 < 8; ++d8) {
        const bf16x8 bv = *(const bf16x8*)&VtB[(d8 * 16 + l15) * VSTR + k2 * 32 + lg * 8];
        accO[d8] = __builtin_amdgcn_mfma_f32_16x16x32_bf16(pa, bv, accO[d8], 0, 0, 0);
      }
    }
    __syncthreads();   // protect K/Vt before next stage
  }

  // ---- epilogue: normalize, store f32 (in-place over Q: block-exclusive rows)
#pragma unroll
  for (int j = 0; j < 4; ++j) {
    const float inv = 1.f / l_j[j];
    const size_t base = (((size_t)(b * CS + q0 + w * 16 + lg * 4 + j)) * CH + h) * CHD;
#pragma unroll
    for (int d8 = 0; d8 < 8; ++d8)
      O[base + d8 * 16 + l15] = accO[d8][j] * inv;
  }
}

// ---------------------------------------------------------------------------
extern "C" void kernel_launch(void* const* d_in, const int* in_sizes, int n_in,
                              void* d_out, int out_size, void* d_ws, size_t ws_size,
                              hipStream_t stream)
{
  const float* x  = (const float*)d_in[0];
  const float* wq = (const float*)d_in[1];
  const float* wk = (const float*)d_in[2];
  const float* wv = (const float*)d_in[3];
  const float* wo = (const float*)d_in[4];
  const float* fc = (const float*)d_in[5];
  const float* fs = (const float*)d_in[6];
  float* out = (float*)d_out;

  float* q = (float*)d_ws;
  float* k = q + (size_t)CB * CS * CH * CHD;
  float* v = k + (size_t)CB * CS * CKV * CHD;

  const int M = CB * CS;  // 4096
  dim3 blk(256);

  gemm_rr_bf16<<<dim3(CH * CHD / 64, M / 64), blk, 0, stream>>>(x, wq, q, M, CH * CHD, CD);
  gemm_rr_bf16<<<dim3(CKV * CHD / 64, M / 64), blk, 0, stream>>>(x, wk, k, M, CKV * CHD, CD);
  gemm_rr_bf16<<<dim3(CKV * CHD / 64, M / 64), blk, 0, stream>>>(x, wv, v, M, CKV * CHD, CD);

  const int qpairs = CB * CS * CH * (CHD / 2);
  const int kpairs = CB * CS * CKV * (CHD / 2);
  rope_kernel<<<(qpairs + 255) / 256, 256, 0, stream>>>(q, fc, fs, CH, 0.08838834764831845f, qpairs);
  rope_kernel<<<(kpairs + 255) / 256, 256, 0, stream>>>(k, fc, fs, CKV, 1.0f, kpairs);

  attn_mfma<<<dim3(CS / 64, CH, CB), blk, 0, stream>>>(q, k, v, q);

  gemm_rr_bf16<<<dim3(CD / 64, M / 64), blk, 0, stream>>>(q, wo, out, M, CD, CD);
}

// Round 4
// 572.024 us; speedup vs baseline: 3.5205x; 1.4493x over previous
//
#include <hip/hip_runtime.h>

typedef __attribute__((ext_vector_type(8))) short bf16x8;
typedef __attribute__((ext_vector_type(4))) float f32x4;
typedef __attribute__((ext_vector_type(4))) unsigned short u16x4;

#define DI __device__ __forceinline__

// Problem constants (B,S,D)=(2,2048,2048), H=16, KV=4, HD=128
constexpr int CB = 2, CS = 2048, CD = 2048, CH = 16, CKV = 4, CHD = 128;

DI unsigned short f2bf(float f) {
  unsigned u = __builtin_bit_cast(unsigned, f);
  u += 0x7fffu + ((u >> 16) & 1u);   // RNE
  return (unsigned short)(u >> 16);
}
DI float bf2f(unsigned short h) {
  return __builtin_bit_cast(float, (unsigned)h << 16);
}

// ---------------------------------------------------------------------------
// 128x128-tile GEMM, BK=32, 256 thr = 4 waves (2x2), each wave owns 64x64.
// A: [M][K] (f32 or bf16 per template), B: [K][N] f32, C: [M][N] (bf16 or f32).
// LDS padded to 40 shorts/row (80B): frag ds_read_b128 banks spread (~2-way).
// mfma_f32_16x16x32_bf16 layouts (verified r0/r2):
//   A: row=lane&15, k=(lane>>4)*8+j | B: col=lane&15, k=(lane>>4)*8+j
//   C/D: col=lane&15, row=(lane>>4)*4+reg
// ---------------------------------------------------------------------------
template <bool A_BF16, bool OUT_BF16>
__global__ __launch_bounds__(256) void gemm128(
    const void* __restrict__ Aptr, const float* __restrict__ B,
    void* __restrict__ Cptr, int M, int N, int K)
{
  __shared__ __align__(16) unsigned short As[128][40];
  __shared__ __align__(16) unsigned short Bs[128][40];

  const int t  = threadIdx.x;
  const int w  = t >> 6, l = t & 63;
  const int l15 = l & 15, lg = l >> 4;
  const int wr = w >> 1, wc = w & 1;
  const int m0 = blockIdx.y * 128;
  const int n0 = blockIdx.x * 128;

  // staging assignment: A: 2 thr/row (16 cols each); B: thread -> (n, 16 k's)
  const int ar = t >> 1, ac = (t & 1) << 4;
  const int bn = t & 127, bkh = (t >> 7) << 4;

  const float*          af = A_BF16 ? nullptr : (const float*)Aptr + (size_t)(m0 + ar) * K + ac;
  const unsigned short* ab = A_BF16 ? (const unsigned short*)Aptr + (size_t)(m0 + ar) * K + ac : nullptr;
  const float* bp = B + (size_t)bkh * N + n0 + bn;

  f32x4 acc[4][4];
#pragma unroll
  for (int i = 0; i < 4; ++i)
#pragma unroll
    for (int j = 0; j < 4; ++j) acc[i][j] = (f32x4){0.f, 0.f, 0.f, 0.f};

  for (int kt = 0; kt < K; kt += 32) {
    // ---- global -> regs
    bf16x8 av0, av1;
    if (A_BF16) {
      av0 = *(const bf16x8*)(ab);
      av1 = *(const bf16x8*)(ab + 8);
      ab += 32;
    } else {
      const float4 a0 = *(const float4*)(af);
      const float4 a1 = *(const float4*)(af + 4);
      const float4 a2 = *(const float4*)(af + 8);
      const float4 a3 = *(const float4*)(af + 12);
      af += 32;
      av0[0] = f2bf(a0.x); av0[1] = f2bf(a0.y); av0[2] = f2bf(a0.z); av0[3] = f2bf(a0.w);
      av0[4] = f2bf(a1.x); av0[5] = f2bf(a1.y); av0[6] = f2bf(a1.z); av0[7] = f2bf(a1.w);
      av1[0] = f2bf(a2.x); av1[1] = f2bf(a2.y); av1[2] = f2bf(a2.z); av1[3] = f2bf(a2.w);
      av1[4] = f2bf(a3.x); av1[5] = f2bf(a3.y); av1[6] = f2bf(a3.z); av1[7] = f2bf(a3.w);
    }
    float bv[16];
#pragma unroll
    for (int i = 0; i < 16; ++i) bv[i] = bp[(size_t)i * N];
    bp += (size_t)32 * N;

    __syncthreads();   // previous iteration's frag reads done

    *(bf16x8*)&As[ar][ac]     = av0;
    *(bf16x8*)&As[ar][ac + 8] = av1;
    bf16x8 bw0, bw1;
#pragma unroll
    for (int i = 0; i < 8; ++i) { bw0[i] = f2bf(bv[i]); bw1[i] = f2bf(bv[i + 8]); }
    *(bf16x8*)&Bs[bn][bkh]     = bw0;
    *(bf16x8*)&Bs[bn][bkh + 8] = bw1;

    __syncthreads();   // tiles visible

    bf16x8 aF[4], bF[4];
#pragma unroll
    for (int i = 0; i < 4; ++i) {
      aF[i] = *(const bf16x8*)&As[wr * 64 + i * 16 + l15][lg * 8];
      bF[i] = *(const bf16x8*)&Bs[wc * 64 + i * 16 + l15][lg * 8];
    }
#pragma unroll
    for (int mi = 0; mi < 4; ++mi)
#pragma unroll
      for (int ni = 0; ni < 4; ++ni)
        acc[mi][ni] = __builtin_amdgcn_mfma_f32_16x16x32_bf16(aF[mi], bF[ni], acc[mi][ni], 0, 0, 0);
  }

  // ---- epilogue
#pragma unroll
  for (int mi = 0; mi < 4; ++mi) {
    const int row0 = m0 + wr * 64 + mi * 16 + lg * 4;
#pragma unroll
    for (int j = 0; j < 4; ++j) {
#pragma unroll
      for (int ni = 0; ni < 4; ++ni) {
        const int col = n0 + wc * 64 + ni * 16 + l15;
        const float v = acc[mi][ni][j];
        if (OUT_BF16)
          ((unsigned short*)Cptr)[(size_t)(row0 + j) * N + col] = f2bf(v);
        else
          ((float*)Cptr)[(size_t)(row0 + j) * N + col] = v;
      }
    }
  }
}

// ---------------------------------------------------------------------------
// RoPE in-place on bf16 [B][S][nH][128]; scale folds 1/sqrt(HD) into Q.
// ---------------------------------------------------------------------------
__global__ void rope_bf16(unsigned short* __restrict__ tq,
                          const float* __restrict__ cosT,
                          const float* __restrict__ sinT,
                          int nH, float scale, int total)
{
  int idx = blockIdx.x * blockDim.x + threadIdx.x;
  if (idx >= total) return;
  const int p    = idx & 63;
  const int rest = idx >> 6;                 // = (b*S + s)*nH + h
  const int s    = (rest / nH) & (CS - 1);
  const float c  = cosT[s * 64 + p];
  const float sn = sinT[s * 64 + p];
  unsigned short* ptr = tq + (size_t)rest * CHD;
  const unsigned pair = *(const unsigned*)&ptr[2 * p];
  const float re = bf2f((unsigned short)pair);
  const float im = bf2f((unsigned short)(pair >> 16));
  const unsigned short lo = f2bf((re * c - im * sn) * scale);
  const unsigned short hi = f2bf((re * sn + im * c) * scale);
  *(unsigned*)&ptr[2 * p] = (unsigned)lo | ((unsigned)hi << 16);
}

// ---------------------------------------------------------------------------
// MFMA causal GQA flash attention, all-bf16 I/O, f32 accum.
// Work-balanced: block g handles q-tiles g and 31-g -> 33 K-tiles each.
// 256 thr = 4 waves; wave w owns q-rows w*16..+16 of the 64-row tile.
// K LDS [64][136] (row=key), V LDS transposed [128][72] (row=d),
// P per-wave [16][72]. Q frags loaded directly global->reg (bf16).
// ---------------------------------------------------------------------------
__global__ __launch_bounds__(256) void attn_mfma(
    const unsigned short* __restrict__ Qb, const unsigned short* __restrict__ Kb,
    const unsigned short* __restrict__ Vb, unsigned short* __restrict__ Ob)
{
  constexpr int KSTR = 136, VSTR = 72, PSTR = 72, NT = CS / 64;  // 32
  __shared__ __align__(16) unsigned short KsB[64 * KSTR];
  __shared__ __align__(16) unsigned short VtB[128 * VSTR];
  __shared__ __align__(16) unsigned short PsB[4 * 16 * PSTR];

  const int t   = threadIdx.x;
  const int w   = t >> 6, l = t & 63;
  const int l15 = l & 15, lg = l >> 4;
  const int g = blockIdx.x, h = blockIdx.y, b = blockIdx.z;
  const int kvh = h >> 2;

  // staging coords
  const int skr = t >> 2, skc = (t & 3) << 5;   // K: row, 64B col chunk

#pragma unroll 1
  for (int qi = 0; qi < 2; ++qi) {
    const int qt = qi ? (NT - 1 - g) : g;
    const int q0 = qt * 64;

    // Q frags direct from global
    bf16x8 qf[4];
    {
      const size_t qrow = ((size_t)(b * CS + q0 + w * 16 + l15) * CH + h) * CHD;
#pragma unroll
      for (int kk = 0; kk < 4; ++kk)
        qf[kk] = *(const bf16x8*)&Qb[qrow + kk * 32 + lg * 8];
    }

    f32x4 accO[8];
#pragma unroll
    for (int i = 0; i < 8; ++i) accO[i] = (f32x4){0.f, 0.f, 0.f, 0.f};
    float m_j[4] = {-1e30f, -1e30f, -1e30f, -1e30f};
    float l_j[4] = {0.f, 0.f, 0.f, 0.f};

    for (int kt = 0; kt <= q0; kt += 64) {
      // ---- stage K rows (bf16 copy, 64B/thread)
      {
        const unsigned short* src = Kb + ((size_t)(b * CS + kt + skr) * CKV + kvh) * CHD + skc;
#pragma unroll
        for (int i = 0; i < 4; ++i)
          *(bf16x8*)&KsB[skr * KSTR + skc + i * 8] = *(const bf16x8*)&src[i * 8];
      }
      // ---- stage V transposed (key-pairs -> u32)
      for (int i = t; i < 1024; i += 256) {
        const int kp = i & 31, dg = i >> 5;
        const int r  = kp * 2;
        const unsigned short* s0 = Vb + ((size_t)(b * CS + kt + r) * CKV + kvh) * CHD + dg * 4;
        const u16x4 v0 = *(const u16x4*)s0;
        const u16x4 v1 = *(const u16x4*)(s0 + (size_t)CKV * CHD);
#pragma unroll
        for (int c2 = 0; c2 < 4; ++c2)
          *(unsigned*)&VtB[(dg * 4 + c2) * VSTR + r] =
              (unsigned)(unsigned short)v0[c2] | ((unsigned)(unsigned short)v1[c2] << 16);
      }
      __syncthreads();

      // ---- QK^T: S(16x64) per wave
      f32x4 s[4];
#pragma unroll
      for (int ks = 0; ks < 4; ++ks) s[ks] = (f32x4){0.f, 0.f, 0.f, 0.f};
#pragma unroll
      for (int kk = 0; kk < 4; ++kk)
#pragma unroll
        for (int ks = 0; ks < 4; ++ks) {
          const bf16x8 bf = *(const bf16x8*)&KsB[(ks * 16 + l15) * KSTR + kk * 32 + lg * 8];
          s[ks] = __builtin_amdgcn_mfma_f32_16x16x32_bf16(qf[kk], bf, s[ks], 0, 0, 0);
        }

      // ---- causal mask on diagonal tile
      if (kt == q0) {
        const int qr = q0 + w * 16 + lg * 4;
#pragma unroll
        for (int ks = 0; ks < 4; ++ks) {
          const int kg = kt + ks * 16 + l15;
#pragma unroll
          for (int j = 0; j < 4; ++j)
            if (kg > qr + j) s[ks][j] = -1e30f;
        }
      }

      // ---- online softmax (16-lane-group reduce, 4 rows/lane)
      float rs[4];
#pragma unroll
      for (int j = 0; j < 4; ++j) {
        float mx = fmaxf(fmaxf(s[0][j], s[1][j]), fmaxf(s[2][j], s[3][j]));
        mx = fmaxf(mx, __shfl_xor(mx, 1));
        mx = fmaxf(mx, __shfl_xor(mx, 2));
        mx = fmaxf(mx, __shfl_xor(mx, 4));
        mx = fmaxf(mx, __shfl_xor(mx, 8));
        const float mnew = fmaxf(m_j[j], mx);
        float sum = 0.f;
#pragma unroll
        for (int ks = 0; ks < 4; ++ks) {
          const float p = __expf(s[ks][j] - mnew);
          s[ks][j] = p;
          sum += p;
        }
        sum += __shfl_xor(sum, 1);
        sum += __shfl_xor(sum, 2);
        sum += __shfl_xor(sum, 4);
        sum += __shfl_xor(sum, 8);
        rs[j]  = __expf(m_j[j] - mnew);
        l_j[j] = l_j[j] * rs[j] + sum;
        m_j[j] = mnew;
      }
#pragma unroll
      for (int d8 = 0; d8 < 8; ++d8)
#pragma unroll
        for (int j = 0; j < 4; ++j) accO[d8][j] *= rs[j];

      // ---- P (C-layout) -> per-wave LDS bf16
      unsigned short* Pw = PsB + w * 16 * PSTR;
#pragma unroll
      for (int ks = 0; ks < 4; ++ks)
#pragma unroll
        for (int j = 0; j < 4; ++j)
          Pw[(lg * 4 + j) * PSTR + ks * 16 + l15] = f2bf(s[ks][j]);

      // ---- PV: O(16x128) += P(16x64) @ V(64x128)
#pragma unroll
      for (int k2 = 0; k2 < 2; ++k2) {
        const bf16x8 pa = *(const bf16x8*)&Pw[l15 * PSTR + k2 * 32 + lg * 8];
#pragma unroll
        for (int d8 = 0; d8 < 8; ++d8) {
          const bf16x8 bv = *(const bf16x8*)&VtB[(d8 * 16 + l15) * VSTR + k2 * 32 + lg * 8];
          accO[d8] = __builtin_amdgcn_mfma_f32_16x16x32_bf16(pa, bv, accO[d8], 0, 0, 0);
        }
      }
      __syncthreads();   // protect K/Vt before next stage
    }

    // ---- epilogue: normalize, store bf16 (in-place over Qb; rows exclusive)
#pragma unroll
    for (int j = 0; j < 4; ++j) {
      const float inv = 1.f / l_j[j];
      const size_t base = ((size_t)(b * CS + q0 + w * 16 + lg * 4 + j) * CH + h) * CHD;
#pragma unroll
      for (int d8 = 0; d8 < 8; ++d8)
        Ob[base + d8 * 16 + l15] = f2bf(accO[d8][j] * inv);
    }
  }
}

// ---------------------------------------------------------------------------
extern "C" void kernel_launch(void* const* d_in, const int* in_sizes, int n_in,
                              void* d_out, int out_size, void* d_ws, size_t ws_size,
                              hipStream_t stream)
{
  const float* x  = (const float*)d_in[0];
  const float* wq = (const float*)d_in[1];
  const float* wk = (const float*)d_in[2];
  const float* wv = (const float*)d_in[3];
  const float* wo = (const float*)d_in[4];
  const float* fc = (const float*)d_in[5];
  const float* fs = (const float*)d_in[6];
  float* out = (float*)d_out;

  // workspace (bf16): qb [B,S,H,HD] | kb [B,S,KV,HD] | vb [B,S,KV,HD] = 25.2 MB
  unsigned short* qb = (unsigned short*)d_ws;
  unsigned short* kb = qb + (size_t)CB * CS * CH * CHD;   // +8,388,608
  unsigned short* vb = kb + (size_t)CB * CS * CKV * CHD;  // +2,097,152

  const int M = CB * CS;  // 4096
  dim3 blk(256);

  gemm128<false, true><<<dim3(CH * CHD / 128, M / 128), blk, 0, stream>>>(x, wq, qb, M, CH * CHD, CD);
  gemm128<false, true><<<dim3(CKV * CHD / 128, M / 128), blk, 0, stream>>>(x, wk, kb, M, CKV * CHD, CD);
  gemm128<false, true><<<dim3(CKV * CHD / 128, M / 128), blk, 0, stream>>>(x, wv, vb, M, CKV * CHD, CD);

  const int qpairs = CB * CS * CH * (CHD / 2);
  const int kpairs = CB * CS * CKV * (CHD / 2);
  rope_bf16<<<(qpairs + 255) / 256, 256, 0, stream>>>(qb, fc, fs, CH, 0.08838834764831845f, qpairs);
  rope_bf16<<<(kpairs + 255) / 256, 256, 0, stream>>>(kb, fc, fs, CKV, 1.0f, kpairs);

  attn_mfma<<<dim3(CS / 128, CH, CB), blk, 0, stream>>>(qb, kb, vb, qb);

  gemm128<true, false><<<dim3(CD / 128, M / 128), blk, 0, stream>>>(qb, wo, out, M, CD, CD);
}

// Round 5
// 477.685 us; speedup vs baseline: 4.2158x; 1.1975x over previous
//
#include <hip/hip_runtime.h>

typedef __attribute__((ext_vector_type(8))) short bf16x8;
typedef __attribute__((ext_vector_type(4))) float f32x4;
typedef __attribute__((ext_vector_type(4))) unsigned short u16x4;

#define DI __device__ __forceinline__

// Problem constants (B,S,D)=(2,2048,2048), H=16, KV=4, HD=128
constexpr int CB = 2, CS = 2048, CD = 2048, CH = 16, CKV = 4, CHD = 128;

DI unsigned short f2bf(float f) {
  unsigned u = __builtin_bit_cast(unsigned, f);
  u += 0x7fffu + ((u >> 16) & 1u);   // RNE
  return (unsigned short)(u >> 16);
}
DI float bf2f(unsigned short h) {
  return __builtin_bit_cast(float, (unsigned)h << 16);
}

// async global->LDS, 16B per lane; LDS dest = wave-uniform base + lane*16
#define GLOAD16(g, l) __builtin_amdgcn_global_load_lds(                      \
    (const __attribute__((address_space(1))) unsigned*)(g),                  \
    (__attribute__((address_space(3))) unsigned*)(l), 16, 0, 0)

// ---------------------------------------------------------------------------
// Flat f32 -> bf16 convert, 8 elems/thread.
// ---------------------------------------------------------------------------
__global__ __launch_bounds__(256) void cvt_bf16(const float* __restrict__ in,
                                                unsigned short* __restrict__ out)
{
  const size_t i = ((size_t)blockIdx.x * 256 + threadIdx.x) * 8;
  const float4 a = *(const float4*)&in[i];
  const float4 b = *(const float4*)&in[i + 4];
  bf16x8 v;
  v[0] = f2bf(a.x); v[1] = f2bf(a.y); v[2] = f2bf(a.z); v[3] = f2bf(a.w);
  v[4] = f2bf(b.x); v[5] = f2bf(b.y); v[6] = f2bf(b.z); v[7] = f2bf(b.w);
  *(bf16x8*)&out[i] = v;
}

// ---------------------------------------------------------------------------
// Transpose-convert: W [K][N] f32 -> Wt [N][K] bf16. 64x64 LDS tiles.
// grid = (N/64, K/64), block 256.
// ---------------------------------------------------------------------------
__global__ __launch_bounds__(256) void cvtT_bf16(const float* __restrict__ W,
                                                 unsigned short* __restrict__ Wt,
                                                 int K, int N)
{
  __shared__ __align__(16) unsigned short Ls[64][72];
  const int n0 = blockIdx.x * 64, k0 = blockIdx.y * 64;
  const int t = threadIdx.x;
  const int r = t >> 4, c = (t & 15) << 2;       // read: row r, cols c..c+3
#pragma unroll
  for (int ph = 0; ph < 4; ++ph) {
    const int row = ph * 16 + r;
    const float4 f = *(const float4*)&W[(size_t)(k0 + row) * N + n0 + c];
    Ls[c + 0][row] = f2bf(f.x);
    Ls[c + 1][row] = f2bf(f.y);
    Ls[c + 2][row] = f2bf(f.z);
    Ls[c + 3][row] = f2bf(f.w);
  }
  __syncthreads();
  const int wr = t >> 2, wc = (t & 3) << 4;      // write: n-row wr, k cols wc..+15
  const bf16x8 v0 = *(const bf16x8*)&Ls[wr][wc];
  const bf16x8 v1 = *(const bf16x8*)&Ls[wr][wc + 8];
  *(bf16x8*)&Wt[(size_t)(n0 + wr) * K + k0 + wc]     = v0;
  *(bf16x8*)&Wt[(size_t)(n0 + wr) * K + k0 + wc + 8] = v1;
}

// ---------------------------------------------------------------------------
// m97-style GEMM: C(M,N) = A(M,K) @ Bt(N,K)^T, A/Bt bf16, C f32 or bf16.
// 128x128 tile, BK=32, 256 thr = 4 waves (2x2), 4x4 16x16x32 frags per wave.
// All staging via global_load_lds width 16 (no VGPR round-trip, no converts).
// LDS linear [128][32] shorts per matrix (16 KB total).
// ---------------------------------------------------------------------------
template <bool OUT_BF16>
__global__ __launch_bounds__(256) void gemm_bt(
    const unsigned short* __restrict__ A, const unsigned short* __restrict__ Bt,
    void* __restrict__ Cptr, int M, int N, int K)
{
  __shared__ __align__(16) unsigned short As[128 * 32];
  __shared__ __align__(16) unsigned short Bs[128 * 32];

  const int t = threadIdx.x;
  const int w = t >> 6, l = t & 63;
  const int l15 = l & 15, lg = l >> 4;
  const int wr = w >> 1, wc = w & 1;
  const int m0 = blockIdx.y * 128;
  const int n0 = blockIdx.x * 128;

  // staging: wave w stages rows [w*16, w*16+16) and [64+w*16, ...) of each tile;
  // lane l -> row base + (l>>2), k-part (l&3)*8 shorts (16B). LDS chunk = 1KB.
  const int sr = l >> 2, sc = (l & 3) << 3;
  const unsigned short* aSrc0 = A  + (size_t)(m0 + w * 16 + sr) * K + sc;
  const unsigned short* aSrc1 = A  + (size_t)(m0 + 64 + w * 16 + sr) * K + sc;
  const unsigned short* bSrc0 = Bt + (size_t)(n0 + w * 16 + sr) * K + sc;
  const unsigned short* bSrc1 = Bt + (size_t)(n0 + 64 + w * 16 + sr) * K + sc;
  unsigned short* aDst0 = As + (w * 16) * 32;
  unsigned short* aDst1 = As + (64 + w * 16) * 32;
  unsigned short* bDst0 = Bs + (w * 16) * 32;
  unsigned short* bDst1 = Bs + (64 + w * 16) * 32;

  f32x4 acc[4][4];
#pragma unroll
  for (int i = 0; i < 4; ++i)
#pragma unroll
    for (int j = 0; j < 4; ++j) acc[i][j] = (f32x4){0.f, 0.f, 0.f, 0.f};

  for (int kt = 0; kt < K; kt += 32) {
    GLOAD16(aSrc0 + kt, aDst0);
    GLOAD16(aSrc1 + kt, aDst1);
    GLOAD16(bSrc0 + kt, bDst0);
    GLOAD16(bSrc1 + kt, bDst1);
    __syncthreads();   // drains vmcnt -> tiles visible

    bf16x8 aF[4], bF[4];
#pragma unroll
    for (int i = 0; i < 4; ++i) {
      aF[i] = *(const bf16x8*)&As[(wr * 64 + i * 16 + l15) * 32 + lg * 8];
      bF[i] = *(const bf16x8*)&Bs[(wc * 64 + i * 16 + l15) * 32 + lg * 8];
    }
#pragma unroll
    for (int mi = 0; mi < 4; ++mi)
#pragma unroll
      for (int ni = 0; ni < 4; ++ni)
        acc[mi][ni] = __builtin_amdgcn_mfma_f32_16x16x32_bf16(aF[mi], bF[ni], acc[mi][ni], 0, 0, 0);

    __syncthreads();   // frag reads done before next-iter staging overwrites
  }

  // epilogue: C/D layout col=lane&15, row=(lane>>4)*4+reg
#pragma unroll
  for (int mi = 0; mi < 4; ++mi) {
    const int row0 = m0 + wr * 64 + mi * 16 + lg * 4;
#pragma unroll
    for (int j = 0; j < 4; ++j) {
#pragma unroll
      for (int ni = 0; ni < 4; ++ni) {
        const int col = n0 + wc * 64 + ni * 16 + l15;
        const float v = acc[mi][ni][j];
        if (OUT_BF16)
          ((unsigned short*)Cptr)[(size_t)(row0 + j) * N + col] = f2bf(v);
        else
          ((float*)Cptr)[(size_t)(row0 + j) * N + col] = v;
      }
    }
  }
}

// ---------------------------------------------------------------------------
// RoPE in-place on bf16 [B][S][nH][128]; scale folds 1/sqrt(HD) into Q.
// ---------------------------------------------------------------------------
__global__ void rope_bf16(unsigned short* __restrict__ tq,
                          const float* __restrict__ cosT,
                          const float* __restrict__ sinT,
                          int nH, float scale, int total)
{
  int idx = blockIdx.x * blockDim.x + threadIdx.x;
  if (idx >= total) return;
  const int p    = idx & 63;
  const int rest = idx >> 6;                 // = (b*S + s)*nH + h
  const int s    = (rest / nH) & (CS - 1);
  const float c  = cosT[s * 64 + p];
  const float sn = sinT[s * 64 + p];
  unsigned short* ptr = tq + (size_t)rest * CHD;
  const unsigned pair = *(const unsigned*)&ptr[2 * p];
  const float re = bf2f((unsigned short)pair);
  const float im = bf2f((unsigned short)(pair >> 16));
  const unsigned short lo = f2bf((re * c - im * sn) * scale);
  const unsigned short hi = f2bf((re * sn + im * c) * scale);
  *(unsigned*)&ptr[2 * p] = (unsigned)lo | ((unsigned)hi << 16);
}

// ---------------------------------------------------------------------------
// MFMA causal GQA flash attention (unchanged from round 3 — passed).
// ---------------------------------------------------------------------------
__global__ __launch_bounds__(256) void attn_mfma(
    const unsigned short* __restrict__ Qb, const unsigned short* __restrict__ Kb,
    const unsigned short* __restrict__ Vb, unsigned short* __restrict__ Ob)
{
  constexpr int KSTR = 136, VSTR = 72, PSTR = 72, NT = CS / 64;  // 32
  __shared__ __align__(16) unsigned short KsB[64 * KSTR];
  __shared__ __align__(16) unsigned short VtB[128 * VSTR];
  __shared__ __align__(16) unsigned short PsB[4 * 16 * PSTR];

  const int t   = threadIdx.x;
  const int w   = t >> 6, l = t & 63;
  const int l15 = l & 15, lg = l >> 4;
  const int g = blockIdx.x, h = blockIdx.y, b = blockIdx.z;
  const int kvh = h >> 2;

  const int skr = t >> 2, skc = (t & 3) << 5;

#pragma unroll 1
  for (int qi = 0; qi < 2; ++qi) {
    const int qt = qi ? (NT - 1 - g) : g;
    const int q0 = qt * 64;

    bf16x8 qf[4];
    {
      const size_t qrow = ((size_t)(b * CS + q0 + w * 16 + l15) * CH + h) * CHD;
#pragma unroll
      for (int kk = 0; kk < 4; ++kk)
        qf[kk] = *(const bf16x8*)&Qb[qrow + kk * 32 + lg * 8];
    }

    f32x4 accO[8];
#pragma unroll
    for (int i = 0; i < 8; ++i) accO[i] = (f32x4){0.f, 0.f, 0.f, 0.f};
    float m_j[4] = {-1e30f, -1e30f, -1e30f, -1e30f};
    float l_j[4] = {0.f, 0.f, 0.f, 0.f};

    for (int kt = 0; kt <= q0; kt += 64) {
      {
        const unsigned short* src = Kb + ((size_t)(b * CS + kt + skr) * CKV + kvh) * CHD + skc;
#pragma unroll
        for (int i = 0; i < 4; ++i)
          *(bf16x8*)&KsB[skr * KSTR + skc + i * 8] = *(const bf16x8*)&src[i * 8];
      }
      for (int i = t; i < 1024; i += 256) {
        const int kp = i & 31, dg = i >> 5;
        const int r  = kp * 2;
        const unsigned short* s0 = Vb + ((size_t)(b * CS + kt + r) * CKV + kvh) * CHD + dg * 4;
        const u16x4 v0 = *(const u16x4*)s0;
        const u16x4 v1 = *(const u16x4*)(s0 + (size_t)CKV * CHD);
#pragma unroll
        for (int c2 = 0; c2 < 4; ++c2)
          *(unsigned*)&VtB[(dg * 4 + c2) * VSTR + r] =
              (unsigned)(unsigned short)v0[c2] | ((unsigned)(unsigned short)v1[c2] << 16);
      }
      __syncthreads();

      f32x4 s[4];
#pragma unroll
      for (int ks = 0; ks < 4; ++ks) s[ks] = (f32x4){0.f, 0.f, 0.f, 0.f};
#pragma unroll
      for (int kk = 0; kk < 4; ++kk)
#pragma unroll
        for (int ks = 0; ks < 4; ++ks) {
          const bf16x8 bf = *(const bf16x8*)&KsB[(ks * 16 + l15) * KSTR + kk * 32 + lg * 8];
          s[ks] = __builtin_amdgcn_mfma_f32_16x16x32_bf16(qf[kk], bf, s[ks], 0, 0, 0);
        }

      if (kt == q0) {
        const int qr = q0 + w * 16 + lg * 4;
#pragma unroll
        for (int ks = 0; ks < 4; ++ks) {
          const int kg = kt + ks * 16 + l15;
#pragma unroll
          for (int j = 0; j < 4; ++j)
            if (kg > qr + j) s[ks][j] = -1e30f;
        }
      }

      float rs[4];
#pragma unroll
      for (int j = 0; j < 4; ++j) {
        float mx = fmaxf(fmaxf(s[0][j], s[1][j]), fmaxf(s[2][j], s[3][j]));
        mx = fmaxf(mx, __shfl_xor(mx, 1));
        mx = fmaxf(mx, __shfl_xor(mx, 2));
        mx = fmaxf(mx, __shfl_xor(mx, 4));
        mx = fmaxf(mx, __shfl_xor(mx, 8));
        const float mnew = fmaxf(m_j[j], mx);
        float sum = 0.f;
#pragma unroll
        for (int ks = 0; ks < 4; ++ks) {
          const float p = __expf(s[ks][j] - mnew);
          s[ks][j] = p;
          sum += p;
        }
        sum += __shfl_xor(sum, 1);
        sum += __shfl_xor(sum, 2);
        sum += __shfl_xor(sum, 4);
        sum += __shfl_xor(sum, 8);
        rs[j]  = __expf(m_j[j] - mnew);
        l_j[j] = l_j[j] * rs[j] + sum;
        m_j[j] = mnew;
      }
#pragma unroll
      for (int d8 = 0; d8 < 8; ++d8)
#pragma unroll
        for (int j = 0; j < 4; ++j) accO[d8][j] *= rs[j];

      unsigned short* Pw = PsB + w * 16 * PSTR;
#pragma unroll
      for (int ks = 0; ks < 4; ++ks)
#pragma unroll
        for (int j = 0; j < 4; ++j)
          Pw[(lg * 4 + j) * PSTR + ks * 16 + l15] = f2bf(s[ks][j]);

#pragma unroll
      for (int k2 = 0; k2 < 2; ++k2) {
        const bf16x8 pa = *(const bf16x8*)&Pw[l15 * PSTR + k2 * 32 + lg * 8];
#pragma unroll
        for (int d8 = 0; d8 < 8; ++d8) {
          const bf16x8 bv = *(const bf16x8*)&VtB[(d8 * 16 + l15) * VSTR + k2 * 32 + lg * 8];
          accO[d8] = __builtin_amdgcn_mfma_f32_16x16x32_bf16(pa, bv, accO[d8], 0, 0, 0);
        }
      }
      __syncthreads();
    }

#pragma unroll
    for (int j = 0; j < 4; ++j) {
      const float inv = 1.f / l_j[j];
      const size_t base = ((size_t)(b * CS + q0 + w * 16 + lg * 4 + j) * CH + h) * CHD;
#pragma unroll
      for (int d8 = 0; d8 < 8; ++d8)
        Ob[base + d8 * 16 + l15] = f2bf(accO[d8][j] * inv);
    }
  }
}

// ---------------------------------------------------------------------------
extern "C" void kernel_launch(void* const* d_in, const int* in_sizes, int n_in,
                              void* d_out, int out_size, void* d_ws, size_t ws_size,
                              hipStream_t stream)
{
  const float* x  = (const float*)d_in[0];
  const float* wq = (const float*)d_in[1];
  const float* wk = (const float*)d_in[2];
  const float* wv = (const float*)d_in[3];
  const float* wo = (const float*)d_in[4];
  const float* fc = (const float*)d_in[5];
  const float* fs = (const float*)d_in[6];
  float* out = (float*)d_out;

  // ws (bf16 elems): xb 8.4M | qb 8.4M | kb 2.1M | vb 2.1M | wt 4.2M = 50.33 MB
  unsigned short* xb = (unsigned short*)d_ws;
  unsigned short* qb = xb + (size_t)CB * CS * CD;
  unsigned short* kb = qb + (size_t)CB * CS * CH * CHD;
  unsigned short* vb = kb + (size_t)CB * CS * CKV * CHD;
  unsigned short* wt = vb + (size_t)CB * CS * CKV * CHD;

  const int M = CB * CS;  // 4096
  dim3 blk(256);

  // x -> bf16 (8.4M elems, 8/thread)
  cvt_bf16<<<dim3((CB * CS * CD) / (256 * 8)), blk, 0, stream>>>(x, xb);

  // Q = x @ wq
  cvtT_bf16<<<dim3(CH * CHD / 64, CD / 64), blk, 0, stream>>>(wq, wt, CD, CH * CHD);
  gemm_bt<true><<<dim3(CH * CHD / 128, M / 128), blk, 0, stream>>>(xb, wt, qb, M, CH * CHD, CD);
  // K = x @ wk
  cvtT_bf16<<<dim3(CKV * CHD / 64, CD / 64), blk, 0, stream>>>(wk, wt, CD, CKV * CHD);
  gemm_bt<true><<<dim3(CKV * CHD / 128, M / 128), blk, 0, stream>>>(xb, wt, kb, M, CKV * CHD, CD);
  // V = x @ wv
  cvtT_bf16<<<dim3(CKV * CHD / 64, CD / 64), blk, 0, stream>>>(wv, wt, CD, CKV * CHD);
  gemm_bt<true><<<dim3(CKV * CHD / 128, M / 128), blk, 0, stream>>>(xb, wt, vb, M, CKV * CHD, CD);

  const int qpairs = CB * CS * CH * (CHD / 2);
  const int kpairs = CB * CS * CKV * (CHD / 2);
  rope_bf16<<<(qpairs + 255) / 256, 256, 0, stream>>>(qb, fc, fs, CH, 0.08838834764831845f, qpairs);
  rope_bf16<<<(kpairs + 255) / 256, 256, 0, stream>>>(kb, fc, fs, CKV, 1.0f, kpairs);

  attn_mfma<<<dim3(CS / 128, CH, CB), blk, 0, stream>>>(qb, kb, vb, qb);

  // out = attn @ wo
  cvtT_bf16<<<dim3(CD / 64, CD / 64), blk, 0, stream>>>(wo, wt, CD, CD);
  gemm_bt<false><<<dim3(CD / 128, M / 128), blk, 0, stream>>>(qb, wt, out, M, CD, CD);
}

// Round 6
// 368.639 us; speedup vs baseline: 5.4629x; 1.2958x over previous
//
#include <hip/hip_runtime.h>

typedef __attribute__((ext_vector_type(8))) short bf16x8;
typedef __attribute__((ext_vector_type(4))) float f32x4;
typedef __attribute__((ext_vector_type(4))) unsigned short u16x4;

#define DI __device__ __forceinline__

// Problem constants (B,S,D)=(2,2048,2048), H=16, KV=4, HD=128
constexpr int CB = 2, CS = 2048, CD = 2048, CH = 16, CKV = 4, CHD = 128;

DI unsigned short f2bf(float f) {
  unsigned u = __builtin_bit_cast(unsigned, f);
  u += 0x7fffu + ((u >> 16) & 1u);   // RNE
  return (unsigned short)(u >> 16);
}
DI float bf2f(unsigned short h) {
  return __builtin_bit_cast(float, (unsigned)h << 16);
}

// async global->LDS, 16B per lane; LDS dest = wave-uniform base + lane*16
#define GLOAD16(g, l) __builtin_amdgcn_global_load_lds(                      \
    (const __attribute__((address_space(1))) unsigned*)(g),                  \
    (__attribute__((address_space(3))) unsigned*)(l), 16, 0, 0)

// ---------------------------------------------------------------------------
// Flat f32 -> bf16 convert, 8 elems/thread.
// ---------------------------------------------------------------------------
__global__ __launch_bounds__(256) void cvt_bf16(const float* __restrict__ in,
                                                unsigned short* __restrict__ out)
{
  const size_t i = ((size_t)blockIdx.x * 256 + threadIdx.x) * 8;
  const float4 a = *(const float4*)&in[i];
  const float4 b = *(const float4*)&in[i + 4];
  bf16x8 v;
  v[0] = f2bf(a.x); v[1] = f2bf(a.y); v[2] = f2bf(a.z); v[3] = f2bf(a.w);
  v[4] = f2bf(b.x); v[5] = f2bf(b.y); v[6] = f2bf(b.z); v[7] = f2bf(b.w);
  *(bf16x8*)&out[i] = v;
}

// ---------------------------------------------------------------------------
// Transpose-convert: W [K][N] f32 -> Wt [N][K] bf16. 64x64 LDS tiles.
// grid = (N/64, K/64), block 256.
// ---------------------------------------------------------------------------
__global__ __launch_bounds__(256) void cvtT_bf16(const float* __restrict__ W,
                                                 unsigned short* __restrict__ Wt,
                                                 int K, int N)
{
  __shared__ __align__(16) unsigned short Ls[64][72];
  const int n0 = blockIdx.x * 64, k0 = blockIdx.y * 64;
  const int t = threadIdx.x;
  const int r = t >> 4, c = (t & 15) << 2;       // read: row r, cols c..c+3
#pragma unroll
  for (int ph = 0; ph < 4; ++ph) {
    const int row = ph * 16 + r;
    const float4 f = *(const float4*)&W[(size_t)(k0 + row) * N + n0 + c];
    Ls[c + 0][row] = f2bf(f.x);
    Ls[c + 1][row] = f2bf(f.y);
    Ls[c + 2][row] = f2bf(f.z);
    Ls[c + 3][row] = f2bf(f.w);
  }
  __syncthreads();
  const int wr = t >> 2, wc = (t & 3) << 4;      // write: n-row wr, k cols wc..+15
  const bf16x8 v0 = *(const bf16x8*)&Ls[wr][wc];
  const bf16x8 v1 = *(const bf16x8*)&Ls[wr][wc + 8];
  *(bf16x8*)&Wt[(size_t)(n0 + wr) * K + k0 + wc]     = v0;
  *(bf16x8*)&Wt[(size_t)(n0 + wr) * K + k0 + wc + 8] = v1;
}

// ---------------------------------------------------------------------------
// m97-style GEMM: C(M,N) = A(M,K) @ Bt(N,K)^T, A/Bt bf16.
// MODE 0: C f32. MODE 1: C bf16. MODE 2: fused QKV split — cols [0,2048) ->
// Cptr (stride 2048), [2048,2560) -> K2 (stride 512), [2560,3072) -> V2
// (stride 512); boundaries are 128-aligned so each block is single-dest.
// 128x128 tile, BK=32, 4 waves, all staging via global_load_lds width 16.
// ---------------------------------------------------------------------------
template <int MODE>
__global__ __launch_bounds__(256) void gemm_bt(
    const unsigned short* __restrict__ A, const unsigned short* __restrict__ Bt,
    void* __restrict__ Cptr, unsigned short* __restrict__ K2,
    unsigned short* __restrict__ V2, int M, int N, int K)
{
  __shared__ __align__(16) unsigned short As[128 * 32];
  __shared__ __align__(16) unsigned short Bs[128 * 32];

  const int t = threadIdx.x;
  const int w = t >> 6, l = t & 63;
  const int l15 = l & 15, lg = l >> 4;
  const int wr = w >> 1, wc = w & 1;
  const int m0 = blockIdx.y * 128;
  const int n0 = blockIdx.x * 128;

  const int sr = l >> 2, sc = (l & 3) << 3;
  const unsigned short* aSrc0 = A  + (size_t)(m0 + w * 16 + sr) * K + sc;
  const unsigned short* aSrc1 = A  + (size_t)(m0 + 64 + w * 16 + sr) * K + sc;
  const unsigned short* bSrc0 = Bt + (size_t)(n0 + w * 16 + sr) * K + sc;
  const unsigned short* bSrc1 = Bt + (size_t)(n0 + 64 + w * 16 + sr) * K + sc;
  unsigned short* aDst0 = As + (w * 16) * 32;
  unsigned short* aDst1 = As + (64 + w * 16) * 32;
  unsigned short* bDst0 = Bs + (w * 16) * 32;
  unsigned short* bDst1 = Bs + (64 + w * 16) * 32;

  f32x4 acc[4][4];
#pragma unroll
  for (int i = 0; i < 4; ++i)
#pragma unroll
    for (int j = 0; j < 4; ++j) acc[i][j] = (f32x4){0.f, 0.f, 0.f, 0.f};

  for (int kt = 0; kt < K; kt += 32) {
    GLOAD16(aSrc0 + kt, aDst0);
    GLOAD16(aSrc1 + kt, aDst1);
    GLOAD16(bSrc0 + kt, bDst0);
    GLOAD16(bSrc1 + kt, bDst1);
    __syncthreads();   // drains vmcnt -> tiles visible

    bf16x8 aF[4], bF[4];
#pragma unroll
    for (int i = 0; i < 4; ++i) {
      aF[i] = *(const bf16x8*)&As[(wr * 64 + i * 16 + l15) * 32 + lg * 8];
      bF[i] = *(const bf16x8*)&Bs[(wc * 64 + i * 16 + l15) * 32 + lg * 8];
    }
#pragma unroll
    for (int mi = 0; mi < 4; ++mi)
#pragma unroll
      for (int ni = 0; ni < 4; ++ni)
        acc[mi][ni] = __builtin_amdgcn_mfma_f32_16x16x32_bf16(aF[mi], bF[ni], acc[mi][ni], 0, 0, 0);

    __syncthreads();   // frag reads done before next-iter staging overwrites
  }

  // epilogue: C/D layout col=lane&15, row=(lane>>4)*4+reg
  unsigned short* dst16 = nullptr;
  int cstr = N, coff = n0;
  if (MODE == 2) {
    if (n0 < 2048)      { dst16 = (unsigned short*)Cptr; cstr = 2048; coff = n0; }
    else if (n0 < 2560) { dst16 = K2; cstr = 512; coff = n0 - 2048; }
    else                { dst16 = V2; cstr = 512; coff = n0 - 2560; }
  }
#pragma unroll
  for (int mi = 0; mi < 4; ++mi) {
    const int row0 = m0 + wr * 64 + mi * 16 + lg * 4;
#pragma unroll
    for (int j = 0; j < 4; ++j) {
#pragma unroll
      for (int ni = 0; ni < 4; ++ni) {
        const int cl = wc * 64 + ni * 16 + l15;
        const float v = acc[mi][ni][j];
        if (MODE == 0)
          ((float*)Cptr)[(size_t)(row0 + j) * N + n0 + cl] = v;
        else if (MODE == 1)
          ((unsigned short*)Cptr)[(size_t)(row0 + j) * N + n0 + cl] = f2bf(v);
        else
          dst16[(size_t)(row0 + j) * cstr + coff + cl] = f2bf(v);
      }
    }
  }
}

// ---------------------------------------------------------------------------
// RoPE in-place on bf16 [B][S][nH][128]; scale folds 1/sqrt(HD) into Q.
// ---------------------------------------------------------------------------
__global__ void rope_bf16(unsigned short* __restrict__ tq,
                          const float* __restrict__ cosT,
                          const float* __restrict__ sinT,
                          int nH, float scale, int total)
{
  int idx = blockIdx.x * blockDim.x + threadIdx.x;
  if (idx >= total) return;
  const int p    = idx & 63;
  const int rest = idx >> 6;                 // = (b*S + s)*nH + h
  const int s    = (rest / nH) & (CS - 1);
  const float c  = cosT[s * 64 + p];
  const float sn = sinT[s * 64 + p];
  unsigned short* ptr = tq + (size_t)rest * CHD;
  const unsigned pair = *(const unsigned*)&ptr[2 * p];
  const float re = bf2f((unsigned short)pair);
  const float im = bf2f((unsigned short)(pair >> 16));
  const unsigned short lo = f2bf((re * c - im * sn) * scale);
  const unsigned short hi = f2bf((re * sn + im * c) * scale);
  *(unsigned*)&ptr[2 * p] = (unsigned)lo | ((unsigned)hi << 16);
}

// ---------------------------------------------------------------------------
// MFMA causal GQA flash attention with T14 async-STAGE split:
// next tile's K/V global loads issued into registers between LDS-write and
// compute; vmcnt-wait lands at the next iteration's LDS-write, so HBM/L2
// latency hides under QK/softmax/PV. Barriers: 2 per K-tile (unchanged).
// ---------------------------------------------------------------------------
__global__ __launch_bounds__(256) void attn_mfma(
    const unsigned short* __restrict__ Qb, const unsigned short* __restrict__ Kb,
    const unsigned short* __restrict__ Vb, unsigned short* __restrict__ Ob)
{
  constexpr int KSTR = 136, VSTR = 72, PSTR = 72, NT = CS / 64;  // 32
  __shared__ __align__(16) unsigned short KsB[64 * KSTR];
  __shared__ __align__(16) unsigned short VtB[128 * VSTR];
  __shared__ __align__(16) unsigned short PsB[4 * 16 * PSTR];

  const int t   = threadIdx.x;
  const int w   = t >> 6, l = t & 63;
  const int l15 = l & 15, lg = l >> 4;
  const int g = blockIdx.x, h = blockIdx.y, b = blockIdx.z;
  const int kvh = h >> 2;

  const int skr = t >> 2, skc = (t & 3) << 5;

  bf16x8 kpre[4];
  u16x4  vpre0[4], vpre1[4];

#define ATTN_PREFETCH(KT)                                                          \
  {                                                                                \
    const unsigned short* ksrc =                                                   \
        Kb + ((size_t)(b * CS + (KT) + skr) * CKV + kvh) * CHD + skc;              \
    _Pragma("unroll") for (int i = 0; i < 4; ++i)                                  \
        kpre[i] = *(const bf16x8*)&ksrc[i * 8];                                    \
    _Pragma("unroll") for (int ii = 0; ii < 4; ++ii) {                             \
      const int idx = t + 256 * ii;                                                \
      const int kp = idx & 31, dg = idx >> 5;                                      \
      const unsigned short* vsrc =                                                 \
          Vb + ((size_t)(b * CS + (KT) + kp * 2) * CKV + kvh) * CHD + dg * 4;      \
      vpre0[ii] = *(const u16x4*)vsrc;                                             \
      vpre1[ii] = *(const u16x4*)(vsrc + (size_t)CKV * CHD);                       \
    }                                                                              \
  }

#define ATTN_WRITE_LDS                                                             \
  {                                                                                \
    _Pragma("unroll") for (int i = 0; i < 4; ++i)                                  \
        *(bf16x8*)&KsB[skr * KSTR + skc + i * 8] = kpre[i];                        \
    _Pragma("unroll") for (int ii = 0; ii < 4; ++ii) {                             \
      const int idx = t + 256 * ii;                                                \
      const int kp = idx & 31, dg = idx >> 5;                                      \
      const int r = kp * 2;                                                        \
      _Pragma("unroll") for (int c2 = 0; c2 < 4; ++c2)                             \
        *(unsigned*)&VtB[(dg * 4 + c2) * VSTR + r] =                               \
            (unsigned)(unsigned short)vpre0[ii][c2] |                              \
            ((unsigned)(unsigned short)vpre1[ii][c2] << 16);                       \
    }                                                                              \
  }

#pragma unroll 1
  for (int qi = 0; qi < 2; ++qi) {
    const int qt = qi ? (NT - 1 - g) : g;
    const int q0 = qt * 64;

    bf16x8 qf[4];
    {
      const size_t qrow = ((size_t)(b * CS + q0 + w * 16 + l15) * CH + h) * CHD;
#pragma unroll
      for (int kk = 0; kk < 4; ++kk)
        qf[kk] = *(const bf16x8*)&Qb[qrow + kk * 32 + lg * 8];
    }

    f32x4 accO[8];
#pragma unroll
    for (int i = 0; i < 8; ++i) accO[i] = (f32x4){0.f, 0.f, 0.f, 0.f};
    float m_j[4] = {-1e30f, -1e30f, -1e30f, -1e30f};
    float l_j[4] = {0.f, 0.f, 0.f, 0.f};

    ATTN_PREFETCH(0);

    for (int kt = 0; kt <= q0; kt += 64) {
      __syncthreads();             // prev tile's LDS reads done -> safe to write
      ATTN_WRITE_LDS;
      if (kt + 64 <= q0) ATTN_PREFETCH(kt + 64);
      __syncthreads();             // tiles visible

      f32x4 s[4];
#pragma unroll
      for (int ks = 0; ks < 4; ++ks) s[ks] = (f32x4){0.f, 0.f, 0.f, 0.f};
#pragma unroll
      for (int kk = 0; kk < 4; ++kk)
#pragma unroll
        for (int ks = 0; ks < 4; ++ks) {
          const bf16x8 bf = *(const bf16x8*)&KsB[(ks * 16 + l15) * KSTR + kk * 32 + lg * 8];
          s[ks] = __builtin_amdgcn_mfma_f32_16x16x32_bf16(qf[kk], bf, s[ks], 0, 0, 0);
        }

      if (kt == q0) {
        const int qr = q0 + w * 16 + lg * 4;
#pragma unroll
        for (int ks = 0; ks < 4; ++ks) {
          const int kg = kt + ks * 16 + l15;
#pragma unroll
          for (int j = 0; j < 4; ++j)
            if (kg > qr + j) s[ks][j] = -1e30f;
        }
      }

      float rs[4];
#pragma unroll
      for (int j = 0; j < 4; ++j) {
        float mx = fmaxf(fmaxf(s[0][j], s[1][j]), fmaxf(s[2][j], s[3][j]));
        mx = fmaxf(mx, __shfl_xor(mx, 1));
        mx = fmaxf(mx, __shfl_xor(mx, 2));
        mx = fmaxf(mx, __shfl_xor(mx, 4));
        mx = fmaxf(mx, __shfl_xor(mx, 8));
        const float mnew = fmaxf(m_j[j], mx);
        float sum = 0.f;
#pragma unroll
        for (int ks = 0; ks < 4; ++ks) {
          const float p = __expf(s[ks][j] - mnew);
          s[ks][j] = p;
          sum += p;
        }
        sum += __shfl_xor(sum, 1);
        sum += __shfl_xor(sum, 2);
        sum += __shfl_xor(sum, 4);
        sum += __shfl_xor(sum, 8);
        rs[j]  = __expf(m_j[j] - mnew);
        l_j[j] = l_j[j] * rs[j] + sum;
        m_j[j] = mnew;
      }
#pragma unroll
      for (int d8 = 0; d8 < 8; ++d8)
#pragma unroll
        for (int j = 0; j < 4; ++j) accO[d8][j] *= rs[j];

      unsigned short* Pw = PsB + w * 16 * PSTR;
#pragma unroll
      for (int ks = 0; ks < 4; ++ks)
#pragma unroll
        for (int j = 0; j < 4; ++j)
          Pw[(lg * 4 + j) * PSTR + ks * 16 + l15] = f2bf(s[ks][j]);

#pragma unroll
      for (int k2 = 0; k2 < 2; ++k2) {
        const bf16x8 pa = *(const bf16x8*)&Pw[l15 * PSTR + k2 * 32 + lg * 8];
#pragma unroll
        for (int d8 = 0; d8 < 8; ++d8) {
          const bf16x8 bv = *(const bf16x8*)&VtB[(d8 * 16 + l15) * VSTR + k2 * 32 + lg * 8];
          accO[d8] = __builtin_amdgcn_mfma_f32_16x16x32_bf16(pa, bv, accO[d8], 0, 0, 0);
        }
      }
    }

#pragma unroll
    for (int j = 0; j < 4; ++j) {
      const float inv = 1.f / l_j[j];
      const size_t base = ((size_t)(b * CS + q0 + w * 16 + lg * 4 + j) * CH + h) * CHD;
#pragma unroll
      for (int d8 = 0; d8 < 8; ++d8)
        Ob[base + d8 * 16 + l15] = f2bf(accO[d8][j] * inv);
    }
  }
#undef ATTN_PREFETCH
#undef ATTN_WRITE_LDS
}

// ---------------------------------------------------------------------------
extern "C" void kernel_launch(void* const* d_in, const int* in_sizes, int n_in,
                              void* d_out, int out_size, void* d_ws, size_t ws_size,
                              hipStream_t stream)
{
  const float* x  = (const float*)d_in[0];
  const float* wq = (const float*)d_in[1];
  const float* wk = (const float*)d_in[2];
  const float* wv = (const float*)d_in[3];
  const float* wo = (const float*)d_in[4];
  const float* fc = (const float*)d_in[5];
  const float* fs = (const float*)d_in[6];
  float* out = (float*)d_out;

  // ws (bf16): qb 8.4M | kb 2.1M | vb 2.1M | wt 6.3M  = 37.8 MB
  // xb (bf16 x, 16.8 MB) lives in d_out — dead once the fused QKV GEMM ends;
  // d_out is rewritten in full by the final MODE-0 GEMM.
  unsigned short* qb = (unsigned short*)d_ws;
  unsigned short* kb = qb + (size_t)CB * CS * CH * CHD;    // +8,388,608
  unsigned short* vb = kb + (size_t)CB * CS * CKV * CHD;   // +2,097,152
  unsigned short* wt = vb + (size_t)CB * CS * CKV * CHD;   // +2,097,152 (6.3M elems)
  unsigned short* xb = (unsigned short*)d_out;

  const int M = CB * CS;  // 4096
  dim3 blk(256);

  // x -> bf16 (into d_out scratch)
  cvt_bf16<<<dim3((CB * CS * CD) / (256 * 8)), blk, 0, stream>>>(x, xb);

  // wq|wk|wv transposed into one [3072][2048] bf16 buffer
  cvtT_bf16<<<dim3(CD / 64, CD / 64), blk, 0, stream>>>(wq, wt, CD, CD);
  cvtT_bf16<<<dim3((CKV * CHD) / 64, CD / 64), blk, 0, stream>>>(wk, wt + (size_t)2048 * CD, CD, CKV * CHD);
  cvtT_bf16<<<dim3((CKV * CHD) / 64, CD / 64), blk, 0, stream>>>(wv, wt + (size_t)2560 * CD, CD, CKV * CHD);

  // fused QKV projection: [4096,2048] @ [2048,3072] -> qb|kb|vb
  gemm_bt<2><<<dim3(3072 / 128, M / 128), blk, 0, stream>>>(xb, wt, qb, kb, vb, M, 3072, CD);

  const int qpairs = CB * CS * CH * (CHD / 2);
  const int kpairs = CB * CS * CKV * (CHD / 2);
  rope_bf16<<<(qpairs + 255) / 256, 256, 0, stream>>>(qb, fc, fs, CH, 0.08838834764831845f, qpairs);
  rope_bf16<<<(kpairs + 255) / 256, 256, 0, stream>>>(kb, fc, fs, CKV, 1.0f, kpairs);

  attn_mfma<<<dim3(CS / 128, CH, CB), blk, 0, stream>>>(qb, kb, vb, qb);

  // out = attn @ wo (wo^T into wt rows 0..2047; xb dead by now)
  cvtT_bf16<<<dim3(CD / 64, CD / 64), blk, 0, stream>>>(wo, wt, CD, CD);
  gemm_bt<0><<<dim3(CD / 128, M / 128), blk, 0, stream>>>(qb, wt, out, nullptr, nullptr, M, CD, CD);
}